// Round 11
// baseline (386.430 us; speedup 1.0000x reference)
//
#include <hip/hip_runtime.h>
#include <hip/hip_bf16.h>
#include <stdint.h>

#define NEXP 8
#define HD 1024
#define ID 3584
#define NTOK 2048
#define NSLOT 4096          // NTOK * TOPK
#define SLOT_PAD 256
#define NSLOT_ALLOC (NSLOT + SLOT_PAD)
#define WN (NEXP * ID * HD)   // elements per weight tensor = 29,360,128
#define KSPLIT 4
#define KLEN (ID / KSPLIT)    // 896

typedef unsigned short u16;
typedef __attribute__((ext_vector_type(8))) short s16x8;
typedef __attribute__((ext_vector_type(4))) short s16x4;
typedef __attribute__((ext_vector_type(4))) float f32x4;

#define BARRIER() __builtin_amdgcn_s_barrier()
#define LGKM0()   asm volatile("s_waitcnt lgkmcnt(0)" ::: "memory")
#define VMCNT0()  asm volatile("s_waitcnt vmcnt(0)" ::: "memory")
#define SCHEDB()  __builtin_amdgcn_sched_barrier(0)

__device__ __forceinline__ u16 f2bf(float f) {
    __hip_bfloat16 h = __float2bfloat16(f);   // RNE
    union { __hip_bfloat16 h; u16 u; } v; v.h = h; return v.u;
}

__device__ __forceinline__ s16x8 cvt8(f32x4 a, f32x4 b) {
    s16x8 o;
    o[0]=(short)f2bf(a[0]); o[1]=(short)f2bf(a[1]); o[2]=(short)f2bf(a[2]); o[3]=(short)f2bf(a[3]);
    o[4]=(short)f2bf(b[0]); o[5]=(short)f2bf(b[1]); o[6]=(short)f2bf(b[2]); o[7]=(short)f2bf(b[3]);
    return o;
}

__device__ __forceinline__ void glds16(const void* g, void* l) {
    __builtin_amdgcn_global_load_lds((const __attribute__((address_space(1))) unsigned*)g,
                                     (__attribute__((address_space(3))) unsigned*)l, 16, 0, 0);
}

// ---------------- K0: zero counters ----------------
__global__ void init_kernel(int* __restrict__ counts) {
    if (threadIdx.x < 16) counts[threadIdx.x] = 0;   // counts[8] + counts2[8]
}

// ---------------- K1: router (fp32, exact top-2) ----------------
__global__ void router_kernel(const float* __restrict__ x, const float* __restrict__ wg,
                              int* __restrict__ topk_idx, float* __restrict__ topk_w,
                              int* __restrict__ counts) {
    int t = blockIdx.x;
    int lane = threadIdx.x;   // 64 threads = 1 wave
    const float* xr = x + (size_t)t * HD;
    float acc[NEXP];
#pragma unroll
    for (int e = 0; e < NEXP; ++e) acc[e] = 0.f;
#pragma unroll
    for (int i = 0; i < HD / 256; ++i) {
        int h = i * 256 + lane * 4;
        f32x4 xv = *(const f32x4*)(xr + h);
#pragma unroll
        for (int e = 0; e < NEXP; ++e) {
            f32x4 wv = *(const f32x4*)(wg + e * HD + h);
            acc[e] += xv[0]*wv[0] + xv[1]*wv[1] + xv[2]*wv[2] + xv[3]*wv[3];
        }
    }
#pragma unroll
    for (int e = 0; e < NEXP; ++e) {
#pragma unroll
        for (int s = 32; s > 0; s >>= 1) acc[e] += __shfl_xor(acc[e], s, 64);
    }
    if (lane == 0) {
        int b0 = 0; float l0 = acc[0];
#pragma unroll
        for (int e = 1; e < NEXP; ++e) if (acc[e] > l0) { l0 = acc[e]; b0 = e; }
        int b1 = (b0 == 0) ? 1 : 0; float l1 = acc[b1];
#pragma unroll
        for (int e = 0; e < NEXP; ++e) {
            if (e == b0 || e == b1) continue;
            if (acc[e] > l1) { l1 = acc[e]; b1 = e; }
        }
        float w0 = 1.f / (1.f + expf(l1 - l0));   // renormalized top-2 softmax
        float w1 = 1.f - w0;
        topk_idx[2 * t] = b0; topk_idx[2 * t + 1] = b1;
        topk_w[2 * t] = w0;  topk_w[2 * t + 1] = w1;
        atomicAdd(&counts[b0], 1);
        atomicAdd(&counts[b1], 1);
    }
}

// ---------------- K2: exclusive scan + pad rows ----------------
__global__ void scan_kernel(const int* __restrict__ counts, int* __restrict__ offsets,
                            int* __restrict__ rows) {
    if (threadIdx.x == 0) {
        int off = 0;
#pragma unroll
        for (int e = 0; e < NEXP; ++e) { offsets[e] = off; off += counts[e]; }
    }
    if (threadIdx.x < SLOT_PAD) rows[NSLOT + threadIdx.x] = 0;
}

// ---------------- K3: slot assignment ----------------
__global__ void assign_kernel(const int* __restrict__ topk_idx, const int* __restrict__ offsets,
                              int* __restrict__ counts2, int* __restrict__ rows,
                              int* __restrict__ slot_of) {
    int i = blockIdx.x * 256 + threadIdx.x;   // 0..4095
    int e = topk_idx[i];
    int pos = atomicAdd(&counts2[e], 1);
    int slot = offsets[e] + pos;
    rows[slot] = i >> 1;       // token id
    slot_of[i] = slot;
}

// ---------------- K4: fused fp32->bf16 for x, w1, w3 (one dispatch) ----------------
__global__ __launch_bounds__(256)
void cvt3_kernel(const float* __restrict__ x, u16* __restrict__ xbf,
                 const float* __restrict__ w1, u16* __restrict__ w1bf,
                 const float* __restrict__ w3, u16* __restrict__ w3bf) {
    const int NX = NTOK * HD / 8, NW = WN / 8;
    int stride = gridDim.x * 256;
    for (int i = blockIdx.x * 256 + threadIdx.x; i < NX + 2 * NW; i += stride) {
        const float* s; u16* d; int j;
        if (i < NX)            { s = x;  d = xbf;  j = i; }
        else if (i < NX + NW)  { s = w1; d = w1bf; j = i - NX; }
        else                   { s = w3; d = w3bf; j = i - NX - NW; }
        f32x4 v0 = ((const f32x4*)s)[2 * j];
        f32x4 v1 = ((const f32x4*)s)[2 * j + 1];
        ((s16x8*)d)[j] = cvt8(v0, v1);
    }
}

// ---------------- K5: FAT kernel: 4-phase GEMM1 (g,u)+SwiGLU -> h  ||  w2 cvt ----------------
// 8-phase-template port: BM=256, BN=128 dual-B, BK=64, 8 waves, 128 KB LDS.
// Per K-tile 4 phases {(g,k0),(u,k0),(g,k1),(u,k1)}: ds_read subtile + 2 glds rounds,
// barrier, lgkm0+sched_barrier, setprio(1), 16 MFMA, setprio(0), barrier.
// vmcnt(0) once per tile after phase-4 MFMA. Granule swizzle: phys = logical ^ (row&7),
// pre-swizzled glds source + inverse on ds_read. T1 panel remap (8 mt share bid%8).
#define G1_BLOCKS (NEXP * (NTOK / 256) * (ID / 128))   // 1792
#define CVT2_BLOCKS 1024
__global__ __launch_bounds__(512, 2)
void gemm1_kernel(const u16* __restrict__ xbf, const u16* __restrict__ w1bf,
                  const u16* __restrict__ w3bf, const int* __restrict__ counts,
                  const int* __restrict__ offsets, const int* __restrict__ rows,
                  u16* __restrict__ hbuf,
                  const float* __restrict__ w2, u16* __restrict__ w2bf) {
    __shared__ u16 As[2][256][64];    // 64 KB
    __shared__ u16 B1s[2][128][64];   // 32 KB
    __shared__ u16 B3s[2][128][64];   // 32 KB

    if (blockIdx.x >= G1_BLOCKS) {
        // ---- side job: convert w2 to bf16 (overlaps with GEMM1 blocks) ----
        const int stride = CVT2_BLOCKS * 512;
        for (int i = (blockIdx.x - G1_BLOCKS) * 512 + threadIdx.x; i < WN / 8; i += stride) {
            f32x4 v0 = ((const f32x4*)w2)[2 * i];
            f32x4 v1 = ((const f32x4*)w2)[2 * i + 1];
            ((s16x8*)w2bf)[i] = cvt8(v0, v1);
        }
        return;
    }

    // T1 panel decode: panel g = q*8 + (bid&7); mt = (bid>>3)&7. 8 mt-blocks share bid%8.
    int bid = blockIdx.x;
    int q = bid >> 6;             // 0..27
    int rm = bid & 63;
    int mt = rm >> 3;             // 0..7
    int g  = q * 8 + (rm & 7);    // 0..223
    int e  = g / 28;              // NT = ID/128 = 28
    int nt = g - e * 28;

    int n_e = counts[e];
    int m0 = mt * 256;
    if (m0 >= n_e) return;
    int off = offsets[e];
    int n0 = nt * 128;

    int tid = threadIdx.x;
    int lane = tid & 63;
    int wid = tid >> 6;           // 0..7

    // staging geometry: one glds round = 512 thr x 16B = 64 rows of 128B; wave wid
    // covers rows roundbase + wid*8 + (lane>>3), phys granule lane&7.
    // source logical granule = phys ^ (row&7) = (lane&7) ^ (lane>>3).
    int rsub = lane >> 3;                    // 0..7
    int srcg = ((lane & 7) ^ rsub) * 8;      // pre-swizzled source offset (elems)

    const u16* srcA[4];
#pragma unroll
    for (int qq = 0; qq < 4; ++qq) {
        int rl = qq * 64 + wid * 8 + rsub;
        int tok = rows[off + m0 + rl];       // SLOT_PAD=256 guarantees in-bounds
        srcA[qq] = xbf + (size_t)tok * HD + srcg;
    }
    const u16 *srcB1[2], *srcB3[2];
#pragma unroll
    for (int qq = 0; qq < 2; ++qq) {
        int rl = qq * 64 + wid * 8 + rsub;
        srcB1[qq] = w1bf + ((size_t)e * ID + n0 + rl) * HD + srcg;
        srcB3[qq] = w3bf + ((size_t)e * ID + n0 + rl) * HD + srcg;
    }

    f32x4 accg[8][2] = {}, accu[8][2] = {};
    int wm = (wid >> 2) * 128;    // 0 / 128
    int wn = (wid & 3) * 32;      // 0/32/64/96
    int lr = lane & 15;
    int kk = lane >> 4;           // 0..3
    int ks0 = ((kk)     ^ (lr & 7)) * 8;   // k-slice 0: logical granule kk
    int ks1 = ((4 + kk) ^ (lr & 7)) * 8;   // k-slice 1: logical granule 4+kk

    // prologue: tile 0 -> buf 0 (8 rounds), full drain once
#pragma unroll
    for (int qq = 0; qq < 4; ++qq) glds16(srcA[qq], &As[0][qq * 64 + wid * 8][0]);
#pragma unroll
    for (int qq = 0; qq < 2; ++qq) {
        glds16(srcB1[qq], &B1s[0][qq * 64 + wid * 8][0]);
        glds16(srcB3[qq], &B3s[0][qq * 64 + wid * 8][0]);
    }
    VMCNT0();
    BARRIER();

    const int NKT = HD / 64;  // 16
    s16x8 a0[8], a1[8], bfr[2];
    for (int kt = 0; kt < NKT; ++kt) {
        int cur = kt & 1, nxt = cur ^ 1;
        bool more = (kt + 1) < NKT;
        int nk = (kt + 1) * 64;

        // ---- phase 1: (g, k0) ----
#pragma unroll
        for (int f = 0; f < 8; ++f) a0[f] = *(const s16x8*)&As[cur][wm + f * 16 + lr][ks0];
#pragma unroll
        for (int fn = 0; fn < 2; ++fn) bfr[fn] = *(const s16x8*)&B1s[cur][wn + fn * 16 + lr][ks0];
        if (more) {
            glds16(srcA[0] + nk, &As[nxt][0 * 64 + wid * 8][0]);
            glds16(srcA[1] + nk, &As[nxt][1 * 64 + wid * 8][0]);
        }
        BARRIER(); LGKM0(); SCHEDB();
        __builtin_amdgcn_s_setprio(1);
#pragma unroll
        for (int f = 0; f < 8; ++f)
#pragma unroll
            for (int fn = 0; fn < 2; ++fn)
                accg[f][fn] = __builtin_amdgcn_mfma_f32_16x16x32_bf16(a0[f], bfr[fn], accg[f][fn], 0, 0, 0);
        __builtin_amdgcn_s_setprio(0);
        BARRIER();

        // ---- phase 2: (u, k0) — A k0 frags reused from regs ----
#pragma unroll
        for (int fn = 0; fn < 2; ++fn) bfr[fn] = *(const s16x8*)&B3s[cur][wn + fn * 16 + lr][ks0];
        if (more) {
            glds16(srcA[2] + nk, &As[nxt][2 * 64 + wid * 8][0]);
            glds16(srcA[3] + nk, &As[nxt][3 * 64 + wid * 8][0]);
        }
        BARRIER(); LGKM0(); SCHEDB();
        __builtin_amdgcn_s_setprio(1);
#pragma unroll
        for (int f = 0; f < 8; ++f)
#pragma unroll
            for (int fn = 0; fn < 2; ++fn)
                accu[f][fn] = __builtin_amdgcn_mfma_f32_16x16x32_bf16(a0[f], bfr[fn], accu[f][fn], 0, 0, 0);
        __builtin_amdgcn_s_setprio(0);
        BARRIER();

        // ---- phase 3: (g, k1) ----
#pragma unroll
        for (int f = 0; f < 8; ++f) a1[f] = *(const s16x8*)&As[cur][wm + f * 16 + lr][ks1];
#pragma unroll
        for (int fn = 0; fn < 2; ++fn) bfr[fn] = *(const s16x8*)&B1s[cur][wn + fn * 16 + lr][ks1];
        if (more) {
            glds16(srcB1[0] + nk, &B1s[nxt][0 * 64 + wid * 8][0]);
            glds16(srcB1[1] + nk, &B1s[nxt][1 * 64 + wid * 8][0]);
        }
        BARRIER(); LGKM0(); SCHEDB();
        __builtin_amdgcn_s_setprio(1);
#pragma unroll
        for (int f = 0; f < 8; ++f)
#pragma unroll
            for (int fn = 0; fn < 2; ++fn)
                accg[f][fn] = __builtin_amdgcn_mfma_f32_16x16x32_bf16(a1[f], bfr[fn], accg[f][fn], 0, 0, 0);
        __builtin_amdgcn_s_setprio(0);
        BARRIER();

        // ---- phase 4: (u, k1) ----
#pragma unroll
        for (int fn = 0; fn < 2; ++fn) bfr[fn] = *(const s16x8*)&B3s[cur][wn + fn * 16 + lr][ks1];
        if (more) {
            glds16(srcB3[0] + nk, &B3s[nxt][0 * 64 + wid * 8][0]);
            glds16(srcB3[1] + nk, &B3s[nxt][1 * 64 + wid * 8][0]);
        }
        BARRIER(); LGKM0(); SCHEDB();
        __builtin_amdgcn_s_setprio(1);
#pragma unroll
        for (int f = 0; f < 8; ++f)
#pragma unroll
            for (int fn = 0; fn < 2; ++fn)
                accu[f][fn] = __builtin_amdgcn_mfma_f32_16x16x32_bf16(a1[f], bfr[fn], accu[f][fn], 0, 0, 0);
        __builtin_amdgcn_s_setprio(0);
        VMCNT0();     // drain next-tile rounds: oldest 6 of 8 are >=1 phase old (covered)
        BARRIER();
    }

    // epilogue: SwiGLU + bf16 store
    int lc = lane & 15;
    int lr4 = (lane >> 4) * 4;
#pragma unroll
    for (int fm = 0; fm < 8; ++fm) {
#pragma unroll
        for (int r = 0; r < 4; ++r) {
            int row = wm + fm * 16 + lr4 + r;
            if (m0 + row < n_e) {
                size_t base = (size_t)(off + m0 + row) * ID + n0 + wn;
#pragma unroll
                for (int fn = 0; fn < 2; ++fn) {
                    float g2 = accg[fm][fn][r];
                    float u = accu[fm][fn][r];
                    float hv = g2 * u / (1.f + expf(-g2));   // silu(g)*u
                    hbuf[base + fn * 16 + lc] = f2bf(hv);
                }
            }
        }
    }
}

// ---------------- K6: GEMM2 h @ w2bf^T -> per-slot fp32, split-K x4, 8-wave (R10) ----------------
__global__ __launch_bounds__(512, 4)
void gemm2_kernel(const u16* __restrict__ hbuf, const u16* __restrict__ w2bf,
                  const int* __restrict__ counts, const int* __restrict__ offsets,
                  float* __restrict__ out2) {
    int bid = blockIdx.x;
    int e = bid & 7;
    int inner = bid >> 3;        // 0..511
    int mt = inner >> 5;         // 0..15
    int r2 = inner & 31;
    int nt = r2 >> 2;            // 0..7
    int ks = r2 & 3;             // 0..3

    int n_e = counts[e];
    int m0 = mt * 128;
    if (m0 >= n_e) return;
    int off = offsets[e];
    int n0 = nt * 128;
    int kbase = ks * KLEN;

    __shared__ u16 As[128][32];   // 8 KB
    __shared__ u16 Bs[128][32];   // 8 KB

    int tid = threadIdx.x;
    int lane = tid & 63;
    int wid = tid >> 6;           // 0..7

    int srow = wid * 16 + (lane >> 2);
    int chunk = ((lane & 3) ^ ((srow >> 1) & 3)) * 8;
    const u16* srcA = hbuf + (size_t)(off + m0 + srow) * ID + kbase + chunk;
    const u16* srcB = w2bf + ((size_t)e * HD + n0 + srow) * ID + kbase + chunk;

    f32x4 acc[4][2] = {};
    int wm = (wid >> 2) * 64;
    int wn = (wid & 3) * 32;
    int lr = lane & 15;
    int k8sw = ((lane >> 4) ^ ((lr >> 1) & 3)) * 8;

    for (int k0 = 0; k0 < KLEN; k0 += 32) {
        glds16(srcA + k0, &As[wid * 16][0]);
        glds16(srcB + k0, &Bs[wid * 16][0]);
        __syncthreads();
        s16x8 a[4], b[2];
#pragma unroll
        for (int f = 0; f < 4; ++f)
            a[f] = *(const s16x8*)&As[wm + f * 16 + lr][k8sw];
#pragma unroll
        for (int f = 0; f < 2; ++f)
            b[f] = *(const s16x8*)&Bs[wn + f * 16 + lr][k8sw];
#pragma unroll
        for (int fm = 0; fm < 4; ++fm)
#pragma unroll
            for (int fn = 0; fn < 2; ++fn)
                acc[fm][fn] = __builtin_amdgcn_mfma_f32_16x16x32_bf16(a[fm], b[fn], acc[fm][fn], 0, 0, 0);
        __syncthreads();
    }

    float* outp = out2 + (size_t)ks * NSLOT_ALLOC * HD;
    int lc = lane & 15;
    int lr4 = (lane >> 4) * 4;
#pragma unroll
    for (int fm = 0; fm < 4; ++fm) {
#pragma unroll
        for (int r = 0; r < 4; ++r) {
            int row = wm + fm * 16 + lr4 + r;
            if (m0 + row < n_e) {
                float* dst = outp + (size_t)(off + m0 + row) * HD + n0 + wn;
#pragma unroll
                for (int fn = 0; fn < 2; ++fn)
                    dst[fn * 16 + lc] = acc[fm][fn][r];
            }
        }
    }
}

// ---------------- K7: weighted combine (sums KSPLIT partials) ----------------
__global__ void combine_kernel(const float* __restrict__ out2, const int* __restrict__ slot_of,
                               const float* __restrict__ topk_w, float* __restrict__ y) {
    int i = blockIdx.x * 256 + threadIdx.x;   // over NTOK*HD/4
    int t = i >> 8;           // HD/4 = 256 float4 per token
    int c = i & 255;
    int s0 = slot_of[2 * t], s1 = slot_of[2 * t + 1];
    float w0 = topk_w[2 * t], w1 = topk_w[2 * t + 1];
    f32x4 o = {0.f, 0.f, 0.f, 0.f};
#pragma unroll
    for (int ks = 0; ks < KSPLIT; ++ks) {
        const float* p = out2 + (size_t)ks * NSLOT_ALLOC * HD;
        f32x4 a = ((const f32x4*)(p + (size_t)s0 * HD))[c];
        f32x4 b = ((const f32x4*)(p + (size_t)s1 * HD))[c];
#pragma unroll
        for (int j = 0; j < 4; ++j) o[j] += w0 * a[j] + w1 * b[j];
    }
    ((f32x4*)(y + (size_t)t * HD))[c] = o;
}

extern "C" void kernel_launch(void* const* d_in, const int* in_sizes, int n_in,
                              void* d_out, int out_size, void* d_ws, size_t ws_size,
                              hipStream_t stream) {
    (void)in_sizes; (void)n_in; (void)out_size; (void)ws_size;
    const float* x  = (const float*)d_in[0];
    const float* wg = (const float*)d_in[1];
    const float* w1 = (const float*)d_in[2];
    const float* w3 = (const float*)d_in[3];
    const float* w2 = (const float*)d_in[4];
    float* y = (float*)d_out;

    char* ws = (char*)d_ws;
    int*   counts   = (int*)(ws + 0);       // 8 ints
    int*   counts2  = (int*)(ws + 32);      // 8 ints
    int*   offsets  = (int*)(ws + 64);      // 8 ints
    int*   topk_idx = (int*)(ws + 128);                        // 4096 ints
    float* topk_w   = (float*)(ws + 128 + (size_t)NSLOT * 4);  // 4096 floats
    int*   rows     = (int*)(ws + 128 + (size_t)NSLOT * 8);    // 4352 ints
    int*   slot_of  = (int*)(ws + 128 + (size_t)NSLOT * 8 + (size_t)NSLOT_ALLOC * 4);
    size_t off_xbf = 128 + (size_t)NSLOT * 12 + (size_t)NSLOT_ALLOC * 4;
    off_xbf = (off_xbf + 255) & ~(size_t)255;
    u16* xbf = (u16*)(ws + off_xbf);
    size_t off_h = off_xbf + (size_t)NTOK * HD * 2;
    u16* hbuf = (u16*)(ws + off_h);
    size_t off_w1 = off_h + (size_t)NSLOT_ALLOC * ID * 2;
    u16* w1bf = (u16*)(ws + off_w1);
    size_t off_w3 = off_w1 + (size_t)WN * 2;
    u16* w3bf = (u16*)(ws + off_w3);
    size_t off_w2 = off_w3 + (size_t)WN * 2;
    u16* w2bf = (u16*)(ws + off_w2);
    size_t off_o2 = off_w2 + (size_t)WN * 2;
    float* out2 = (float*)(ws + off_o2);    // KSPLIT partial buffers

    init_kernel<<<1, 64, 0, stream>>>(counts);
    router_kernel<<<NTOK, 64, 0, stream>>>(x, wg, topk_idx, topk_w, counts);
    scan_kernel<<<1, 256, 0, stream>>>(counts, offsets, rows);
    assign_kernel<<<NSLOT / 256, 256, 0, stream>>>(topk_idx, offsets, counts2, rows, slot_of);
    cvt3_kernel<<<4096, 256, 0, stream>>>(x, xbf, w1, w1bf, w3, w3bf);
    gemm1_kernel<<<G1_BLOCKS + CVT2_BLOCKS, 512, 0, stream>>>(xbf, w1bf, w3bf, counts, offsets, rows, hbuf, w2, w2bf);
    gemm2_kernel<<<NEXP * (NTOK / 128) * (HD / 128) * KSPLIT, 512, 0, stream>>>(hbuf, w2bf, counts, offsets, out2);
    combine_kernel<<<(NTOK * HD / 4) / 256, 256, 0, stream>>>(out2, slot_of, topk_w, y);
}

// Round 13
// 379.148 us; speedup vs baseline: 1.0192x; 1.0192x over previous
//
#include <hip/hip_runtime.h>
#include <hip/hip_bf16.h>
#include <stdint.h>

#define NEXP 8
#define HD 1024
#define ID 3584
#define NTOK 2048
#define NSLOT 4096          // NTOK * TOPK
#define SLOT_PAD 256
#define NSLOT_ALLOC (NSLOT + SLOT_PAD)
#define WN (NEXP * ID * HD)   // elements per weight tensor = 29,360,128
#define KSPLIT 4
#define KLEN (ID / KSPLIT)    // 896

typedef unsigned short u16;
typedef __attribute__((ext_vector_type(8))) short s16x8;
typedef __attribute__((ext_vector_type(4))) short s16x4;
typedef __attribute__((ext_vector_type(4))) float f32x4;

#define BARRIER() __builtin_amdgcn_s_barrier()
#define LGKM0()   asm volatile("s_waitcnt lgkmcnt(0)" ::: "memory")
#define VMCNT(n)  asm volatile("s_waitcnt vmcnt(" #n ")" ::: "memory")
#define SCHEDB()  __builtin_amdgcn_sched_barrier(0)

__device__ __forceinline__ u16 f2bf(float f) {
    __hip_bfloat16 h = __float2bfloat16(f);   // RNE
    union { __hip_bfloat16 h; u16 u; } v; v.h = h; return v.u;
}

__device__ __forceinline__ s16x8 cvt8(f32x4 a, f32x4 b) {
    s16x8 o;
    o[0]=(short)f2bf(a[0]); o[1]=(short)f2bf(a[1]); o[2]=(short)f2bf(a[2]); o[3]=(short)f2bf(a[3]);
    o[4]=(short)f2bf(b[0]); o[5]=(short)f2bf(b[1]); o[6]=(short)f2bf(b[2]); o[7]=(short)f2bf(b[3]);
    return o;
}

__device__ __forceinline__ void glds16(const void* g, void* l) {
    __builtin_amdgcn_global_load_lds((const __attribute__((address_space(1))) unsigned*)g,
                                     (__attribute__((address_space(3))) unsigned*)l, 16, 0, 0);
}

// ---------------- K0: zero counters ----------------
__global__ void init_kernel(int* __restrict__ counts) {
    if (threadIdx.x < 16) counts[threadIdx.x] = 0;   // counts[8] + counts2[8]
}

// ---------------- K1: router (fp32, exact top-2) ----------------
__global__ void router_kernel(const float* __restrict__ x, const float* __restrict__ wg,
                              int* __restrict__ topk_idx, float* __restrict__ topk_w,
                              int* __restrict__ counts) {
    int t = blockIdx.x;
    int lane = threadIdx.x;   // 64 threads = 1 wave
    const float* xr = x + (size_t)t * HD;
    float acc[NEXP];
#pragma unroll
    for (int e = 0; e < NEXP; ++e) acc[e] = 0.f;
#pragma unroll
    for (int i = 0; i < HD / 256; ++i) {
        int h = i * 256 + lane * 4;
        f32x4 xv = *(const f32x4*)(xr + h);
#pragma unroll
        for (int e = 0; e < NEXP; ++e) {
            f32x4 wv = *(const f32x4*)(wg + e * HD + h);
            acc[e] += xv[0]*wv[0] + xv[1]*wv[1] + xv[2]*wv[2] + xv[3]*wv[3];
        }
    }
#pragma unroll
    for (int e = 0; e < NEXP; ++e) {
#pragma unroll
        for (int s = 32; s > 0; s >>= 1) acc[e] += __shfl_xor(acc[e], s, 64);
    }
    if (lane == 0) {
        int b0 = 0; float l0 = acc[0];
#pragma unroll
        for (int e = 1; e < NEXP; ++e) if (acc[e] > l0) { l0 = acc[e]; b0 = e; }
        int b1 = (b0 == 0) ? 1 : 0; float l1 = acc[b1];
#pragma unroll
        for (int e = 0; e < NEXP; ++e) {
            if (e == b0 || e == b1) continue;
            if (acc[e] > l1) { l1 = acc[e]; b1 = e; }
        }
        float w0 = 1.f / (1.f + expf(l1 - l0));   // renormalized top-2 softmax
        float w1 = 1.f - w0;
        topk_idx[2 * t] = b0; topk_idx[2 * t + 1] = b1;
        topk_w[2 * t] = w0;  topk_w[2 * t + 1] = w1;
        atomicAdd(&counts[b0], 1);
        atomicAdd(&counts[b1], 1);
    }
}

// ---------------- K2: exclusive scan + pad rows ----------------
__global__ void scan_kernel(const int* __restrict__ counts, int* __restrict__ offsets,
                            int* __restrict__ rows) {
    if (threadIdx.x == 0) {
        int off = 0;
#pragma unroll
        for (int e = 0; e < NEXP; ++e) { offsets[e] = off; off += counts[e]; }
    }
    if (threadIdx.x < SLOT_PAD) rows[NSLOT + threadIdx.x] = 0;
}

// ---------------- K3: slot assignment ----------------
__global__ void assign_kernel(const int* __restrict__ topk_idx, const int* __restrict__ offsets,
                              int* __restrict__ counts2, int* __restrict__ rows,
                              int* __restrict__ slot_of) {
    int i = blockIdx.x * 256 + threadIdx.x;   // 0..4095
    int e = topk_idx[i];
    int pos = atomicAdd(&counts2[e], 1);
    int slot = offsets[e] + pos;
    rows[slot] = i >> 1;       // token id
    slot_of[i] = slot;
}

// ---------------- K4: fused fp32->bf16 for x, w1, w3 (one dispatch) ----------------
__global__ __launch_bounds__(256)
void cvt3_kernel(const float* __restrict__ x, u16* __restrict__ xbf,
                 const float* __restrict__ w1, u16* __restrict__ w1bf,
                 const float* __restrict__ w3, u16* __restrict__ w3bf) {
    const int NX = NTOK * HD / 8, NW = WN / 8;
    int stride = gridDim.x * 256;
    for (int i = blockIdx.x * 256 + threadIdx.x; i < NX + 2 * NW; i += stride) {
        const float* s; u16* d; int j;
        if (i < NX)            { s = x;  d = xbf;  j = i; }
        else if (i < NX + NW)  { s = w1; d = w1bf; j = i - NX; }
        else                   { s = w3; d = w3bf; j = i - NX - NW; }
        f32x4 v0 = ((const f32x4*)s)[2 * j];
        f32x4 v1 = ((const f32x4*)s)[2 * j + 1];
        ((s16x8*)d)[j] = cvt8(v0, v1);
    }
}

// ---------------- K5: FAT kernel: 4-phase GEMM1 (g,u)+SwiGLU -> h  ||  w2 cvt ----------------
// R12 + last-tile drain fix: phase-1 wait is vmcnt(2) while prefetching, vmcnt(0) on the
// final tile (no A01 issued -> vmcnt(2) was a no-op and B3 writes raced phase-2 reads).
#define G1_BLOCKS (NEXP * (NTOK / 256) * (ID / 128))   // 1792
#define CVT2_BLOCKS 1024
__global__ __launch_bounds__(512, 2)
void gemm1_kernel(const u16* __restrict__ xbf, const u16* __restrict__ w1bf,
                  const u16* __restrict__ w3bf, const int* __restrict__ counts,
                  const int* __restrict__ offsets, const int* __restrict__ rows,
                  u16* __restrict__ hbuf,
                  const float* __restrict__ w2, u16* __restrict__ w2bf) {
    __shared__ u16 As[2][256][64];    // 64 KB
    __shared__ u16 B1s[2][128][64];   // 32 KB
    __shared__ u16 B3s[2][128][64];   // 32 KB

    if (blockIdx.x >= G1_BLOCKS) {
        // ---- side job: convert w2 to bf16 (overlaps with GEMM1 blocks) ----
        const int stride = CVT2_BLOCKS * 512;
        for (int i = (blockIdx.x - G1_BLOCKS) * 512 + threadIdx.x; i < WN / 8; i += stride) {
            f32x4 v0 = ((const f32x4*)w2)[2 * i];
            f32x4 v1 = ((const f32x4*)w2)[2 * i + 1];
            ((s16x8*)w2bf)[i] = cvt8(v0, v1);
        }
        return;
    }

    // T1 panel decode: panel g = q*8 + (bid&7); mt = (bid>>3)&7. 8 mt-blocks share bid%8.
    int bid = blockIdx.x;
    int q = bid >> 6;             // 0..27
    int rm = bid & 63;
    int mt = rm >> 3;             // 0..7
    int g  = q * 8 + (rm & 7);    // 0..223
    int e  = g / 28;              // NT = ID/128 = 28
    int nt = g - e * 28;

    int n_e = counts[e];
    int m0 = mt * 256;
    if (m0 >= n_e) return;
    int off = offsets[e];
    int n0 = nt * 128;

    int tid = threadIdx.x;
    int lane = tid & 63;
    int wid = tid >> 6;           // 0..7

    // staging geometry: one glds round = 512 thr x 16B = 64 rows of 128B; wave wid
    // covers rows roundbase + wid*8 + (lane>>3), phys granule lane&7.
    // source logical granule = phys ^ (row&7) = (lane&7) ^ (lane>>3).
    int rsub = lane >> 3;                    // 0..7
    int srcg = ((lane & 7) ^ rsub) * 8;      // pre-swizzled source offset (elems)

    const u16* srcA[4];
#pragma unroll
    for (int qq = 0; qq < 4; ++qq) {
        int rl = qq * 64 + wid * 8 + rsub;
        int tok = rows[off + m0 + rl];       // SLOT_PAD=256 guarantees in-bounds
        srcA[qq] = xbf + (size_t)tok * HD + srcg;
    }
    const u16 *srcB1[2], *srcB3[2];
#pragma unroll
    for (int qq = 0; qq < 2; ++qq) {
        int rl = qq * 64 + wid * 8 + rsub;
        srcB1[qq] = w1bf + ((size_t)e * ID + n0 + rl) * HD + srcg;
        srcB3[qq] = w3bf + ((size_t)e * ID + n0 + rl) * HD + srcg;
    }

    f32x4 accg[8][2] = {}, accu[8][2] = {};
    int wm = (wid >> 2) * 128;    // 0 / 128
    int wn = (wid & 3) * 32;      // 0/32/64/96
    int lr = lane & 15;
    int kk = lane >> 4;           // 0..3
    int ks0 = ((kk)     ^ (lr & 7)) * 8;   // k-slice 0: logical granule kk
    int ks1 = ((4 + kk) ^ (lr & 7)) * 8;   // k-slice 1: logical granule 4+kk

    // prologue: tile 0 -> buf 0 (8 rounds), full drain once (outside loop: allowed)
#pragma unroll
    for (int qq = 0; qq < 4; ++qq) glds16(srcA[qq], &As[0][qq * 64 + wid * 8][0]);
#pragma unroll
    for (int qq = 0; qq < 2; ++qq) {
        glds16(srcB1[qq], &B1s[0][qq * 64 + wid * 8][0]);
        glds16(srcB3[qq], &B3s[0][qq * 64 + wid * 8][0]);
    }
    VMCNT(0);
    BARRIER();

    const int NKT = HD / 64;  // 16
    s16x8 a0[8], a1[8], bfr[2];
    for (int kt = 0; kt < NKT; ++kt) {
        int cur = kt & 1, nxt = cur ^ 1;
        bool more = (kt + 1) < NKT;
        int nk = (kt + 1) * 64;

        // ---- phase 1: (g, k0) ----  [needs As[cur], B1s[cur]]
#pragma unroll
        for (int f = 0; f < 8; ++f) a0[f] = *(const s16x8*)&As[cur][wm + f * 16 + lr][ks0];
#pragma unroll
        for (int fn = 0; fn < 2; ++fn) bfr[fn] = *(const s16x8*)&B1s[cur][wn + fn * 16 + lr][ks0];
        if (more) {
            glds16(srcA[0] + nk, &As[nxt][0 * 64 + wid * 8][0]);
            glds16(srcA[1] + nk, &As[nxt][1 * 64 + wid * 8][0]);
        }
        BARRIER(); LGKM0(); SCHEDB();
        __builtin_amdgcn_s_setprio(1);
#pragma unroll
        for (int f = 0; f < 8; ++f)
#pragma unroll
            for (int fn = 0; fn < 2; ++fn)
                accg[f][fn] = __builtin_amdgcn_mfma_f32_16x16x32_bf16(a0[f], bfr[fn], accg[f][fn], 0, 0, 0);
        __builtin_amdgcn_s_setprio(0);
        // counted drain of B3 (issued prev ph4). With prefetch in flight the 2 newest
        // (A01) may remain; on the LAST tile nothing was issued -> must drain to 0
        // (R12 bug: vmcnt(2) was a no-op there and phase 2 read racing B3 writes).
        if (more) { VMCNT(2); } else { VMCNT(0); }
        BARRIER();

        // ---- phase 2: (u, k0) — A k0 frags reused from regs; B3s[cur] now safe ----
#pragma unroll
        for (int fn = 0; fn < 2; ++fn) bfr[fn] = *(const s16x8*)&B3s[cur][wn + fn * 16 + lr][ks0];
        if (more) {
            glds16(srcA[2] + nk, &As[nxt][2 * 64 + wid * 8][0]);
            glds16(srcA[3] + nk, &As[nxt][3 * 64 + wid * 8][0]);
        }
        BARRIER(); LGKM0(); SCHEDB();
        __builtin_amdgcn_s_setprio(1);
#pragma unroll
        for (int f = 0; f < 8; ++f)
#pragma unroll
            for (int fn = 0; fn < 2; ++fn)
                accu[f][fn] = __builtin_amdgcn_mfma_f32_16x16x32_bf16(a0[f], bfr[fn], accu[f][fn], 0, 0, 0);
        __builtin_amdgcn_s_setprio(0);
        BARRIER();

        // ---- phase 3: (g, k1) ----
#pragma unroll
        for (int f = 0; f < 8; ++f) a1[f] = *(const s16x8*)&As[cur][wm + f * 16 + lr][ks1];
#pragma unroll
        for (int fn = 0; fn < 2; ++fn) bfr[fn] = *(const s16x8*)&B1s[cur][wn + fn * 16 + lr][ks1];
        if (more) {
            glds16(srcB1[0] + nk, &B1s[nxt][0 * 64 + wid * 8][0]);
            glds16(srcB1[1] + nk, &B1s[nxt][1 * 64 + wid * 8][0]);
        }
        BARRIER(); LGKM0(); SCHEDB();
        __builtin_amdgcn_s_setprio(1);
#pragma unroll
        for (int f = 0; f < 8; ++f)
#pragma unroll
            for (int fn = 0; fn < 2; ++fn)
                accg[f][fn] = __builtin_amdgcn_mfma_f32_16x16x32_bf16(a1[f], bfr[fn], accg[f][fn], 0, 0, 0);
        __builtin_amdgcn_s_setprio(0);
        BARRIER();

        // ---- phase 4: (u, k1) ----
#pragma unroll
        for (int fn = 0; fn < 2; ++fn) bfr[fn] = *(const s16x8*)&B3s[cur][wn + fn * 16 + lr][ks1];
        if (more) {
            glds16(srcB3[0] + nk, &B3s[nxt][0 * 64 + wid * 8][0]);
            glds16(srcB3[1] + nk, &B3s[nxt][1 * 64 + wid * 8][0]);
        }
        BARRIER(); LGKM0(); SCHEDB();
        __builtin_amdgcn_s_setprio(1);
#pragma unroll
        for (int f = 0; f < 8; ++f)
#pragma unroll
            for (int fn = 0; fn < 2; ++fn)
                accu[f][fn] = __builtin_amdgcn_mfma_f32_16x16x32_bf16(a1[f], bfr[fn], accu[f][fn], 0, 0, 0);
        __builtin_amdgcn_s_setprio(0);
        VMCNT(2);     // drains A01/A23/B1 (1-3 phases old); B3 stays in flight,
                      // drained at next tile's phase-1 wait
        BARRIER();
    }

    // epilogue: SwiGLU + bf16 store
    int lc = lane & 15;
    int lr4 = (lane >> 4) * 4;
#pragma unroll
    for (int fm = 0; fm < 8; ++fm) {
#pragma unroll
        for (int r = 0; r < 4; ++r) {
            int row = wm + fm * 16 + lr4 + r;
            if (m0 + row < n_e) {
                size_t base = (size_t)(off + m0 + row) * ID + n0 + wn;
#pragma unroll
                for (int fn = 0; fn < 2; ++fn) {
                    float g2 = accg[fm][fn][r];
                    float u = accu[fm][fn][r];
                    float hv = g2 * u / (1.f + expf(-g2));   // silu(g)*u
                    hbuf[base + fn * 16 + lc] = f2bf(hv);
                }
            }
        }
    }
}

// ---------------- K6: GEMM2 h @ w2bf^T -> per-slot fp32, split-K x4, 8-wave (R10) ----------------
__global__ __launch_bounds__(512, 4)
void gemm2_kernel(const u16* __restrict__ hbuf, const u16* __restrict__ w2bf,
                  const int* __restrict__ counts, const int* __restrict__ offsets,
                  float* __restrict__ out2) {
    int bid = blockIdx.x;
    int e = bid & 7;
    int inner = bid >> 3;        // 0..511
    int mt = inner >> 5;         // 0..15
    int r2 = inner & 31;
    int nt = r2 >> 2;            // 0..7
    int ks = r2 & 3;             // 0..3

    int n_e = counts[e];
    int m0 = mt * 128;
    if (m0 >= n_e) return;
    int off = offsets[e];
    int n0 = nt * 128;
    int kbase = ks * KLEN;

    __shared__ u16 As[128][32];   // 8 KB
    __shared__ u16 Bs[128][32];   // 8 KB

    int tid = threadIdx.x;
    int lane = tid & 63;
    int wid = tid >> 6;           // 0..7

    int srow = wid * 16 + (lane >> 2);
    int chunk = ((lane & 3) ^ ((srow >> 1) & 3)) * 8;
    const u16* srcA = hbuf + (size_t)(off + m0 + srow) * ID + kbase + chunk;
    const u16* srcB = w2bf + ((size_t)e * HD + n0 + srow) * ID + kbase + chunk;

    f32x4 acc[4][2] = {};
    int wm = (wid >> 2) * 64;
    int wn = (wid & 3) * 32;
    int lr = lane & 15;
    int k8sw = ((lane >> 4) ^ ((lr >> 1) & 3)) * 8;

    for (int k0 = 0; k0 < KLEN; k0 += 32) {
        glds16(srcA + k0, &As[wid * 16][0]);
        glds16(srcB + k0, &Bs[wid * 16][0]);
        __syncthreads();
        s16x8 a[4], b[2];
#pragma unroll
        for (int f = 0; f < 4; ++f)
            a[f] = *(const s16x8*)&As[wm + f * 16 + lr][k8sw];
#pragma unroll
        for (int f = 0; f < 2; ++f)
            b[f] = *(const s16x8*)&Bs[wn + f * 16 + lr][k8sw];
#pragma unroll
        for (int fm = 0; fm < 4; ++fm)
#pragma unroll
            for (int fn = 0; fn < 2; ++fn)
                acc[fm][fn] = __builtin_amdgcn_mfma_f32_16x16x32_bf16(a[fm], b[fn], acc[fm][fn], 0, 0, 0);
        __syncthreads();
    }

    float* outp = out2 + (size_t)ks * NSLOT_ALLOC * HD;
    int lc = lane & 15;
    int lr4 = (lane >> 4) * 4;
#pragma unroll
    for (int fm = 0; fm < 4; ++fm) {
#pragma unroll
        for (int r = 0; r < 4; ++r) {
            int row = wm + fm * 16 + lr4 + r;
            if (m0 + row < n_e) {
                float* dst = outp + (size_t)(off + m0 + row) * HD + n0 + wn;
#pragma unroll
                for (int fn = 0; fn < 2; ++fn)
                    dst[fn * 16 + lc] = acc[fm][fn][r];
            }
        }
    }
}

// ---------------- K7: weighted combine (sums KSPLIT partials) ----------------
__global__ void combine_kernel(const float* __restrict__ out2, const int* __restrict__ slot_of,
                               const float* __restrict__ topk_w, float* __restrict__ y) {
    int i = blockIdx.x * 256 + threadIdx.x;   // over NTOK*HD/4
    int t = i >> 8;           // HD/4 = 256 float4 per token
    int c = i & 255;
    int s0 = slot_of[2 * t], s1 = slot_of[2 * t + 1];
    float w0 = topk_w[2 * t], w1 = topk_w[2 * t + 1];
    f32x4 o = {0.f, 0.f, 0.f, 0.f};
#pragma unroll
    for (int ks = 0; ks < KSPLIT; ++ks) {
        const float* p = out2 + (size_t)ks * NSLOT_ALLOC * HD;
        f32x4 a = ((const f32x4*)(p + (size_t)s0 * HD))[c];
        f32x4 b = ((const f32x4*)(p + (size_t)s1 * HD))[c];
#pragma unroll
        for (int j = 0; j < 4; ++j) o[j] += w0 * a[j] + w1 * b[j];
    }
    ((f32x4*)(y + (size_t)t * HD))[c] = o;
}

extern "C" void kernel_launch(void* const* d_in, const int* in_sizes, int n_in,
                              void* d_out, int out_size, void* d_ws, size_t ws_size,
                              hipStream_t stream) {
    (void)in_sizes; (void)n_in; (void)out_size; (void)ws_size;
    const float* x  = (const float*)d_in[0];
    const float* wg = (const float*)d_in[1];
    const float* w1 = (const float*)d_in[2];
    const float* w3 = (const float*)d_in[3];
    const float* w2 = (const float*)d_in[4];
    float* y = (float*)d_out;

    char* ws = (char*)d_ws;
    int*   counts   = (int*)(ws + 0);       // 8 ints
    int*   counts2  = (int*)(ws + 32);      // 8 ints
    int*   offsets  = (int*)(ws + 64);      // 8 ints
    int*   topk_idx = (int*)(ws + 128);                        // 4096 ints
    float* topk_w   = (float*)(ws + 128 + (size_t)NSLOT * 4);  // 4096 floats
    int*   rows     = (int*)(ws + 128 + (size_t)NSLOT * 8);    // 4352 ints
    int*   slot_of  = (int*)(ws + 128 + (size_t)NSLOT * 8 + (size_t)NSLOT_ALLOC * 4);
    size_t off_xbf = 128 + (size_t)NSLOT * 12 + (size_t)NSLOT_ALLOC * 4;
    off_xbf = (off_xbf + 255) & ~(size_t)255;
    u16* xbf = (u16*)(ws + off_xbf);
    size_t off_h = off_xbf + (size_t)NTOK * HD * 2;
    u16* hbuf = (u16*)(ws + off_h);
    size_t off_w1 = off_h + (size_t)NSLOT_ALLOC * ID * 2;
    u16* w1bf = (u16*)(ws + off_w1);
    size_t off_w3 = off_w1 + (size_t)WN * 2;
    u16* w3bf = (u16*)(ws + off_w3);
    size_t off_w2 = off_w3 + (size_t)WN * 2;
    u16* w2bf = (u16*)(ws + off_w2);
    size_t off_o2 = off_w2 + (size_t)WN * 2;
    float* out2 = (float*)(ws + off_o2);    // KSPLIT partial buffers

    init_kernel<<<1, 64, 0, stream>>>(counts);
    router_kernel<<<NTOK, 64, 0, stream>>>(x, wg, topk_idx, topk_w, counts);
    scan_kernel<<<1, 256, 0, stream>>>(counts, offsets, rows);
    assign_kernel<<<NSLOT / 256, 256, 0, stream>>>(topk_idx, offsets, counts2, rows, slot_of);
    cvt3_kernel<<<4096, 256, 0, stream>>>(x, xbf, w1, w1bf, w3, w3bf);
    gemm1_kernel<<<G1_BLOCKS + CVT2_BLOCKS, 512, 0, stream>>>(xbf, w1bf, w3bf, counts, offsets, rows, hbuf, w2, w2bf);
    gemm2_kernel<<<NEXP * (NTOK / 128) * (HD / 128) * KSPLIT, 512, 0, stream>>>(hbuf, w2bf, counts, offsets, out2);
    combine_kernel<<<(NTOK * HD / 4) / 256, 256, 0, stream>>>(out2, slot_of, topk_w, y);
}

// Round 14
// 341.183 us; speedup vs baseline: 1.1326x; 1.1113x over previous
//
#include <hip/hip_runtime.h>
#include <hip/hip_bf16.h>
#include <stdint.h>

#define NEXP 8
#define HD 1024
#define ID 3584
#define NTOK 2048
#define NSLOT 4096          // NTOK * TOPK
#define SLOT_PAD 256
#define NSLOT_ALLOC (NSLOT + SLOT_PAD)
#define WN (NEXP * ID * HD)   // elements per weight tensor = 29,360,128
#define KSPLIT 4
#define KLEN (ID / KSPLIT)    // 896

typedef unsigned short u16;
typedef __attribute__((ext_vector_type(8))) short s16x8;
typedef __attribute__((ext_vector_type(4))) short s16x4;
typedef __attribute__((ext_vector_type(4))) float f32x4;

__device__ __forceinline__ u16 f2bf(float f) {
    __hip_bfloat16 h = __float2bfloat16(f);   // RNE
    union { __hip_bfloat16 h; u16 u; } v; v.h = h; return v.u;
}

__device__ __forceinline__ s16x8 cvt8(f32x4 a, f32x4 b) {
    s16x8 o;
    o[0]=(short)f2bf(a[0]); o[1]=(short)f2bf(a[1]); o[2]=(short)f2bf(a[2]); o[3]=(short)f2bf(a[3]);
    o[4]=(short)f2bf(b[0]); o[5]=(short)f2bf(b[1]); o[6]=(short)f2bf(b[2]); o[7]=(short)f2bf(b[3]);
    return o;
}

__device__ __forceinline__ void glds16(const void* g, void* l) {
    __builtin_amdgcn_global_load_lds((const __attribute__((address_space(1))) unsigned*)g,
                                     (__attribute__((address_space(3))) unsigned*)l, 16, 0, 0);
}

// ---------------- K0: zero counters ----------------
__global__ void init_kernel(int* __restrict__ counts) {
    if (threadIdx.x < 16) counts[threadIdx.x] = 0;   // counts[8] + counts2[8]
}

// ---------------- K1: router (fp32, exact top-2) ----------------
__global__ void router_kernel(const float* __restrict__ x, const float* __restrict__ wg,
                              int* __restrict__ topk_idx, float* __restrict__ topk_w,
                              int* __restrict__ counts) {
    int t = blockIdx.x;
    int lane = threadIdx.x;   // 64 threads = 1 wave
    const float* xr = x + (size_t)t * HD;
    float acc[NEXP];
#pragma unroll
    for (int e = 0; e < NEXP; ++e) acc[e] = 0.f;
#pragma unroll
    for (int i = 0; i < HD / 256; ++i) {
        int h = i * 256 + lane * 4;
        f32x4 xv = *(const f32x4*)(xr + h);
#pragma unroll
        for (int e = 0; e < NEXP; ++e) {
            f32x4 wv = *(const f32x4*)(wg + e * HD + h);
            acc[e] += xv[0]*wv[0] + xv[1]*wv[1] + xv[2]*wv[2] + xv[3]*wv[3];
        }
    }
#pragma unroll
    for (int e = 0; e < NEXP; ++e) {
#pragma unroll
        for (int s = 32; s > 0; s >>= 1) acc[e] += __shfl_xor(acc[e], s, 64);
    }
    if (lane == 0) {
        int b0 = 0; float l0 = acc[0];
#pragma unroll
        for (int e = 1; e < NEXP; ++e) if (acc[e] > l0) { l0 = acc[e]; b0 = e; }
        int b1 = (b0 == 0) ? 1 : 0; float l1 = acc[b1];
#pragma unroll
        for (int e = 0; e < NEXP; ++e) {
            if (e == b0 || e == b1) continue;
            if (acc[e] > l1) { l1 = acc[e]; b1 = e; }
        }
        float w0 = 1.f / (1.f + expf(l1 - l0));   // renormalized top-2 softmax
        float w1 = 1.f - w0;
        topk_idx[2 * t] = b0; topk_idx[2 * t + 1] = b1;
        topk_w[2 * t] = w0;  topk_w[2 * t + 1] = w1;
        atomicAdd(&counts[b0], 1);
        atomicAdd(&counts[b1], 1);
    }
}

// ---------------- K2: exclusive scan + pad rows ----------------
__global__ void scan_kernel(const int* __restrict__ counts, int* __restrict__ offsets,
                            int* __restrict__ rows) {
    if (threadIdx.x == 0) {
        int off = 0;
#pragma unroll
        for (int e = 0; e < NEXP; ++e) { offsets[e] = off; off += counts[e]; }
    }
    if (threadIdx.x < SLOT_PAD) rows[NSLOT + threadIdx.x] = 0;
}

// ---------------- K3: slot assignment ----------------
__global__ void assign_kernel(const int* __restrict__ topk_idx, const int* __restrict__ offsets,
                              int* __restrict__ counts2, int* __restrict__ rows,
                              int* __restrict__ slot_of) {
    int i = blockIdx.x * 256 + threadIdx.x;   // 0..4095
    int e = topk_idx[i];
    int pos = atomicAdd(&counts2[e], 1);
    int slot = offsets[e] + pos;
    rows[slot] = i >> 1;       // token id
    slot_of[i] = slot;
}

// ---------------- K4: fused fp32->bf16 for x, w1, w3 (one dispatch) ----------------
__global__ __launch_bounds__(256)
void cvt3_kernel(const float* __restrict__ x, u16* __restrict__ xbf,
                 const float* __restrict__ w1, u16* __restrict__ w1bf,
                 const float* __restrict__ w3, u16* __restrict__ w3bf) {
    const int NX = NTOK * HD / 8, NW = WN / 8;
    int stride = gridDim.x * 256;
    for (int i = blockIdx.x * 256 + threadIdx.x; i < NX + 2 * NW; i += stride) {
        const float* s; u16* d; int j;
        if (i < NX)            { s = x;  d = xbf;  j = i; }
        else if (i < NX + NW)  { s = w1; d = w1bf; j = i - NX; }
        else                   { s = w3; d = w3bf; j = i - NX - NW; }
        f32x4 v0 = ((const f32x4*)s)[2 * j];
        f32x4 v1 = ((const f32x4*)s)[2 * j + 1];
        ((s16x8*)d)[j] = cvt8(v0, v1);
    }
}

// ---------------- K5: FAT kernel: GEMM1 (g,u)+SwiGLU -> h  ||  w2 cvt ----------------
// R9 2-barrier structure, BK=64: halves barrier/drain EVENTS (16 steps vs 32).
// 128x128 tile, 4 waves, 48 KB LDS, [128][64] tiles with 8-granule XOR swizzle
// phys = logical ^ (row&7) — identical mapping HW-verified conflict-free in R13.
// T1 panel-XCD remap (16 mt-blocks share bid%8). Fat w2-cvt side job.
#define G1_BLOCKS (NEXP * (NTOK / 128) * (ID / 128))   // 3584
#define CVT2_BLOCKS 1024
__global__ __launch_bounds__(256, 2)
void gemm1_kernel(const u16* __restrict__ xbf, const u16* __restrict__ w1bf,
                  const u16* __restrict__ w3bf, const int* __restrict__ counts,
                  const int* __restrict__ offsets, const int* __restrict__ rows,
                  u16* __restrict__ hbuf,
                  const float* __restrict__ w2, u16* __restrict__ w2bf) {
    __shared__ u16 As[128][64];    // 16 KB
    __shared__ u16 B1s[128][64];   // 16 KB
    __shared__ u16 B3s[128][64];   // 16 KB

    if (blockIdx.x >= G1_BLOCKS) {
        // ---- side job: convert w2 to bf16 (overlaps with GEMM1 blocks) ----
        const int stride = CVT2_BLOCKS * 256;
        for (int i = (blockIdx.x - G1_BLOCKS) * 256 + threadIdx.x; i < WN / 8; i += stride) {
            f32x4 v0 = ((const f32x4*)w2)[2 * i];
            f32x4 v1 = ((const f32x4*)w2)[2 * i + 1];
            ((s16x8*)w2bf)[i] = cvt8(v0, v1);
        }
        return;
    }

    // T1 panel-XCD decode: panel g = gq*8 + (bid&7), mt = (bid>>3)&15.
    int bid = blockIdx.x;
    int gq = bid >> 7;            // 0..27
    int rm = bid & 127;
    int mt = rm >> 3;             // 0..15
    int g  = gq * 8 + (rm & 7);   // 0..223
    int e  = g / 28;              // NT = ID/128 = 28
    int nt = g - e * 28;

    int n_e = counts[e];
    int m0 = mt * 128;
    if (m0 >= n_e) return;
    int off = offsets[e];
    int n0 = nt * 128;

    int tid = threadIdx.x;
    int lane = tid & 63;
    int wid = tid >> 6;           // 0..3

    // staging: wave wid stages rows [32*wid, 32*wid+32) of each [128][64] tile,
    // 4 glds/tile (8 rows x 8 granules per glds). phys granule = lane&7,
    // source granule = (lane&7) ^ (row&7), row&7 = lane>>3 (slab bases %8 == 0).
    int rsub = lane >> 3;                       // 0..7
    int chunk = ((lane & 7) ^ rsub) * 8;        // pre-swizzled source offset (elems)
    int srow = wid * 32 + rsub;

    const u16 *srcA[4], *srcB1[4], *srcB3[4];
#pragma unroll
    for (int j = 0; j < 4; ++j) {
        int rl = srow + 8 * j;
        int tok = rows[off + m0 + rl];          // pad region guarantees in-bounds
        srcA[j]  = xbf  + (size_t)tok * HD + chunk;
        srcB1[j] = w1bf + ((size_t)e * ID + n0 + rl) * HD + chunk;
        srcB3[j] = w3bf + ((size_t)e * ID + n0 + rl) * HD + chunk;
    }

    f32x4 accg[4][4] = {}, accu[4][4] = {};
    int wm = (wid >> 1) * 64, wn = (wid & 1) * 64;
    int lr = lane & 15;
    int kk = lane >> 4;                          // 0..3
    int ks0 = ((kk)     ^ (lr & 7)) * 8;         // k-half 0 read offset
    int ks1 = ((4 + kk) ^ (lr & 7)) * 8;         // k-half 1 read offset

    for (int k0 = 0; k0 < HD; k0 += 64) {        // 16 steps (was 32)
#pragma unroll
        for (int j = 0; j < 4; ++j) {
            glds16(srcA[j]  + k0, &As[wid * 32 + 8 * j][0]);
            glds16(srcB1[j] + k0, &B1s[wid * 32 + 8 * j][0]);
            glds16(srcB3[j] + k0, &B3s[wid * 32 + 8 * j][0]);
        }
        __syncthreads();
        s16x8 a[4], b1[4], b3[4];
        // ---- k-half 0 ----
#pragma unroll
        for (int f = 0; f < 4; ++f) {
            a[f]  = *(const s16x8*)&As[wm + f * 16 + lr][ks0];
            b1[f] = *(const s16x8*)&B1s[wn + f * 16 + lr][ks0];
            b3[f] = *(const s16x8*)&B3s[wn + f * 16 + lr][ks0];
        }
#pragma unroll
        for (int fm = 0; fm < 4; ++fm)
#pragma unroll
            for (int fn = 0; fn < 4; ++fn) {
                accg[fm][fn] = __builtin_amdgcn_mfma_f32_16x16x32_bf16(a[fm], b1[fn], accg[fm][fn], 0, 0, 0);
                accu[fm][fn] = __builtin_amdgcn_mfma_f32_16x16x32_bf16(a[fm], b3[fn], accu[fm][fn], 0, 0, 0);
            }
        // ---- k-half 1 ----
#pragma unroll
        for (int f = 0; f < 4; ++f) {
            a[f]  = *(const s16x8*)&As[wm + f * 16 + lr][ks1];
            b1[f] = *(const s16x8*)&B1s[wn + f * 16 + lr][ks1];
            b3[f] = *(const s16x8*)&B3s[wn + f * 16 + lr][ks1];
        }
#pragma unroll
        for (int fm = 0; fm < 4; ++fm)
#pragma unroll
            for (int fn = 0; fn < 4; ++fn) {
                accg[fm][fn] = __builtin_amdgcn_mfma_f32_16x16x32_bf16(a[fm], b1[fn], accg[fm][fn], 0, 0, 0);
                accu[fm][fn] = __builtin_amdgcn_mfma_f32_16x16x32_bf16(a[fm], b3[fn], accu[fm][fn], 0, 0, 0);
            }
        __syncthreads();
    }

    // epilogue: SwiGLU + bf16 store
    int lc = lane & 15;
    int lr4 = (lane >> 4) * 4;
#pragma unroll
    for (int fm = 0; fm < 4; ++fm) {
#pragma unroll
        for (int r = 0; r < 4; ++r) {
            int row = wm + fm * 16 + lr4 + r;
            if (m0 + row < n_e) {
                size_t base = (size_t)(off + m0 + row) * ID + n0 + wn;
#pragma unroll
                for (int fn = 0; fn < 4; ++fn) {
                    float g2 = accg[fm][fn][r];
                    float u = accu[fm][fn][r];
                    float hv = g2 * u / (1.f + expf(-g2));   // silu(g)*u
                    hbuf[base + fn * 16 + lc] = f2bf(hv);
                }
            }
        }
    }
}

// ---------------- K6: GEMM2 h @ w2bf^T -> per-slot fp32, split-K x4, BK=64 ----------------
// T1 expert-XCD remap: bid%8 = e. Same 2-barrier BK=64 structure (14 steps).
__global__ __launch_bounds__(256, 2)
void gemm2_kernel(const u16* __restrict__ hbuf, const u16* __restrict__ w2bf,
                  const int* __restrict__ counts, const int* __restrict__ offsets,
                  float* __restrict__ out2) {
    int bid = blockIdx.x;
    int e = bid & 7;
    int inner = bid >> 3;        // 0..511
    int mt = inner >> 5;         // 0..15
    int r2 = inner & 31;
    int nt = r2 >> 2;            // 0..7
    int ks = r2 & 3;             // 0..3

    int n_e = counts[e];
    int m0 = mt * 128;
    if (m0 >= n_e) return;
    int off = offsets[e];
    int n0 = nt * 128;
    int kbase = ks * KLEN;

    __shared__ u16 As[128][64];   // 16 KB
    __shared__ u16 Bs[128][64];   // 16 KB

    int tid = threadIdx.x;
    int lane = tid & 63;
    int wid = tid >> 6;

    int rsub = lane >> 3;
    int chunk = ((lane & 7) ^ rsub) * 8;
    int srow = wid * 32 + rsub;

    const u16 *srcA[4], *srcB[4];
#pragma unroll
    for (int j = 0; j < 4; ++j) {
        int rl = srow + 8 * j;
        srcA[j] = hbuf + (size_t)(off + m0 + rl) * ID + kbase + chunk;
        srcB[j] = w2bf + ((size_t)e * HD + n0 + rl) * ID + kbase + chunk;
    }

    f32x4 acc[4][4] = {};
    int wm = (wid >> 1) * 64, wn = (wid & 1) * 64;
    int lr = lane & 15;
    int kk = lane >> 4;
    int ks0 = ((kk)     ^ (lr & 7)) * 8;
    int ks1 = ((4 + kk) ^ (lr & 7)) * 8;

    for (int k0 = 0; k0 < KLEN; k0 += 64) {      // 14 steps (was 28)
#pragma unroll
        for (int j = 0; j < 4; ++j) {
            glds16(srcA[j] + k0, &As[wid * 32 + 8 * j][0]);
            glds16(srcB[j] + k0, &Bs[wid * 32 + 8 * j][0]);
        }
        __syncthreads();
        s16x8 a[4], b[4];
#pragma unroll
        for (int f = 0; f < 4; ++f) {
            a[f] = *(const s16x8*)&As[wm + f * 16 + lr][ks0];
            b[f] = *(const s16x8*)&Bs[wn + f * 16 + lr][ks0];
        }
#pragma unroll
        for (int fm = 0; fm < 4; ++fm)
#pragma unroll
            for (int fn = 0; fn < 4; ++fn)
                acc[fm][fn] = __builtin_amdgcn_mfma_f32_16x16x32_bf16(a[fm], b[fn], acc[fm][fn], 0, 0, 0);
#pragma unroll
        for (int f = 0; f < 4; ++f) {
            a[f] = *(const s16x8*)&As[wm + f * 16 + lr][ks1];
            b[f] = *(const s16x8*)&Bs[wn + f * 16 + lr][ks1];
        }
#pragma unroll
        for (int fm = 0; fm < 4; ++fm)
#pragma unroll
            for (int fn = 0; fn < 4; ++fn)
                acc[fm][fn] = __builtin_amdgcn_mfma_f32_16x16x32_bf16(a[fm], b[fn], acc[fm][fn], 0, 0, 0);
        __syncthreads();
    }

    float* outp = out2 + (size_t)ks * NSLOT_ALLOC * HD;
    int lc = lane & 15;
    int lr4 = (lane >> 4) * 4;
#pragma unroll
    for (int fm = 0; fm < 4; ++fm) {
#pragma unroll
        for (int r = 0; r < 4; ++r) {
            int row = wm + fm * 16 + lr4 + r;
            if (m0 + row < n_e) {
                float* dst = outp + (size_t)(off + m0 + row) * HD + n0 + wn;
#pragma unroll
                for (int fn = 0; fn < 4; ++fn)
                    dst[fn * 16 + lc] = acc[fm][fn][r];
            }
        }
    }
}

// ---------------- K7: weighted combine (sums KSPLIT partials) ----------------
__global__ void combine_kernel(const float* __restrict__ out2, const int* __restrict__ slot_of,
                               const float* __restrict__ topk_w, float* __restrict__ y) {
    int i = blockIdx.x * 256 + threadIdx.x;   // over NTOK*HD/4
    int t = i >> 8;           // HD/4 = 256 float4 per token
    int c = i & 255;
    int s0 = slot_of[2 * t], s1 = slot_of[2 * t + 1];
    float w0 = topk_w[2 * t], w1 = topk_w[2 * t + 1];
    f32x4 o = {0.f, 0.f, 0.f, 0.f};
#pragma unroll
    for (int ks = 0; ks < KSPLIT; ++ks) {
        const float* p = out2 + (size_t)ks * NSLOT_ALLOC * HD;
        f32x4 a = ((const f32x4*)(p + (size_t)s0 * HD))[c];
        f32x4 b = ((const f32x4*)(p + (size_t)s1 * HD))[c];
#pragma unroll
        for (int j = 0; j < 4; ++j) o[j] += w0 * a[j] + w1 * b[j];
    }
    ((f32x4*)(y + (size_t)t * HD))[c] = o;
}

extern "C" void kernel_launch(void* const* d_in, const int* in_sizes, int n_in,
                              void* d_out, int out_size, void* d_ws, size_t ws_size,
                              hipStream_t stream) {
    (void)in_sizes; (void)n_in; (void)out_size; (void)ws_size;
    const float* x  = (const float*)d_in[0];
    const float* wg = (const float*)d_in[1];
    const float* w1 = (const float*)d_in[2];
    const float* w3 = (const float*)d_in[3];
    const float* w2 = (const float*)d_in[4];
    float* y = (float*)d_out;

    char* ws = (char*)d_ws;
    int*   counts   = (int*)(ws + 0);       // 8 ints
    int*   counts2  = (int*)(ws + 32);      // 8 ints
    int*   offsets  = (int*)(ws + 64);      // 8 ints
    int*   topk_idx = (int*)(ws + 128);                        // 4096 ints
    float* topk_w   = (float*)(ws + 128 + (size_t)NSLOT * 4);  // 4096 floats
    int*   rows     = (int*)(ws + 128 + (size_t)NSLOT * 8);    // 4352 ints
    int*   slot_of  = (int*)(ws + 128 + (size_t)NSLOT * 8 + (size_t)NSLOT_ALLOC * 4);
    size_t off_xbf = 128 + (size_t)NSLOT * 12 + (size_t)NSLOT_ALLOC * 4;
    off_xbf = (off_xbf + 255) & ~(size_t)255;
    u16* xbf = (u16*)(ws + off_xbf);
    size_t off_h = off_xbf + (size_t)NTOK * HD * 2;
    u16* hbuf = (u16*)(ws + off_h);
    size_t off_w1 = off_h + (size_t)NSLOT_ALLOC * ID * 2;
    u16* w1bf = (u16*)(ws + off_w1);
    size_t off_w3 = off_w1 + (size_t)WN * 2;
    u16* w3bf = (u16*)(ws + off_w3);
    size_t off_w2 = off_w3 + (size_t)WN * 2;
    u16* w2bf = (u16*)(ws + off_w2);
    size_t off_o2 = off_w2 + (size_t)WN * 2;
    float* out2 = (float*)(ws + off_o2);    // KSPLIT partial buffers

    init_kernel<<<1, 64, 0, stream>>>(counts);
    router_kernel<<<NTOK, 64, 0, stream>>>(x, wg, topk_idx, topk_w, counts);
    scan_kernel<<<1, 256, 0, stream>>>(counts, offsets, rows);
    assign_kernel<<<NSLOT / 256, 256, 0, stream>>>(topk_idx, offsets, counts2, rows, slot_of);
    cvt3_kernel<<<4096, 256, 0, stream>>>(x, xbf, w1, w1bf, w3, w3bf);
    gemm1_kernel<<<G1_BLOCKS + CVT2_BLOCKS, 256, 0, stream>>>(xbf, w1bf, w3bf, counts, offsets, rows, hbuf, w2, w2bf);
    gemm2_kernel<<<NEXP * (NTOK / 128) * (HD / 128) * KSPLIT, 256, 0, stream>>>(hbuf, w2bf, counts, offsets, out2);
    combine_kernel<<<(NTOK * HD / 4) / 256, 256, 0, stream>>>(out2, slot_of, topk_w, y);
}

// Round 15
// 334.310 us; speedup vs baseline: 1.1559x; 1.0206x over previous
//
#include <hip/hip_runtime.h>
#include <hip/hip_bf16.h>
#include <stdint.h>

#define NEXP 8
#define HD 1024
#define ID 3584
#define NTOK 2048
#define NSLOT 4096          // NTOK * TOPK
#define SLOT_PAD 256
#define NSLOT_ALLOC (NSLOT + SLOT_PAD)
#define WN (NEXP * ID * HD)   // elements per weight tensor = 29,360,128

typedef unsigned short u16;
typedef __attribute__((ext_vector_type(8))) short s16x8;
typedef __attribute__((ext_vector_type(4))) short s16x4;
typedef __attribute__((ext_vector_type(4))) float f32x4;

__device__ __forceinline__ u16 f2bf(float f) {
    __hip_bfloat16 h = __float2bfloat16(f);   // RNE
    union { __hip_bfloat16 h; u16 u; } v; v.h = h; return v.u;
}

__device__ __forceinline__ s16x8 cvt8(f32x4 a, f32x4 b) {
    s16x8 o;
    o[0]=(short)f2bf(a[0]); o[1]=(short)f2bf(a[1]); o[2]=(short)f2bf(a[2]); o[3]=(short)f2bf(a[3]);
    o[4]=(short)f2bf(b[0]); o[5]=(short)f2bf(b[1]); o[6]=(short)f2bf(b[2]); o[7]=(short)f2bf(b[3]);
    return o;
}

__device__ __forceinline__ void glds16(const void* g, void* l) {
    __builtin_amdgcn_global_load_lds((const __attribute__((address_space(1))) unsigned*)g,
                                     (__attribute__((address_space(3))) unsigned*)l, 16, 0, 0);
}

// ---------------- K0: zero counters ----------------
__global__ void init_kernel(int* __restrict__ counts) {
    if (threadIdx.x < 16) counts[threadIdx.x] = 0;   // counts[8] + counts2[8]
}

// ---------------- K1: FAT preprocessing: router (blocks 0..511, 4 tokens/block)
//                  ||  fp32->bf16 cvt of x, w1, w3 (blocks 512..3583, grid-stride)
#define RT_BLOCKS 512
#define CVT3_BLOCKS 3072
__global__ __launch_bounds__(256)
void pre_kernel(const float* __restrict__ x, const float* __restrict__ wg,
                int* __restrict__ topk_idx, float* __restrict__ topk_w,
                int* __restrict__ counts,
                u16* __restrict__ xbf,
                const float* __restrict__ w1, u16* __restrict__ w1bf,
                const float* __restrict__ w3, u16* __restrict__ w3bf) {
    if (blockIdx.x >= RT_BLOCKS) {
        // ---- cvt side: x, w1, w3 ----
        const int NX = NTOK * HD / 8, NW = WN / 8;
        const int stride = CVT3_BLOCKS * 256;
        for (int i = (blockIdx.x - RT_BLOCKS) * 256 + threadIdx.x; i < NX + 2 * NW; i += stride) {
            const float* s; u16* d; int j;
            if (i < NX)            { s = x;  d = xbf;  j = i; }
            else if (i < NX + NW)  { s = w1; d = w1bf; j = i - NX; }
            else                   { s = w3; d = w3bf; j = i - NX - NW; }
            f32x4 v0 = ((const f32x4*)s)[2 * j];
            f32x4 v1 = ((const f32x4*)s)[2 * j + 1];
            ((s16x8*)d)[j] = cvt8(v0, v1);
        }
        return;
    }
    // ---- router: 4 waves/block, 1 token/wave, fp32 exact top-2 ----
    int t = blockIdx.x * 4 + (threadIdx.x >> 6);
    int lane = threadIdx.x & 63;
    const float* xr = x + (size_t)t * HD;
    float acc[NEXP];
#pragma unroll
    for (int e = 0; e < NEXP; ++e) acc[e] = 0.f;
#pragma unroll
    for (int i = 0; i < HD / 256; ++i) {
        int h = i * 256 + lane * 4;
        f32x4 xv = *(const f32x4*)(xr + h);
#pragma unroll
        for (int e = 0; e < NEXP; ++e) {
            f32x4 wv = *(const f32x4*)(wg + e * HD + h);
            acc[e] += xv[0]*wv[0] + xv[1]*wv[1] + xv[2]*wv[2] + xv[3]*wv[3];
        }
    }
#pragma unroll
    for (int e = 0; e < NEXP; ++e) {
#pragma unroll
        for (int s = 32; s > 0; s >>= 1) acc[e] += __shfl_xor(acc[e], s, 64);
    }
    if (lane == 0) {
        int b0 = 0; float l0 = acc[0];
#pragma unroll
        for (int e = 1; e < NEXP; ++e) if (acc[e] > l0) { l0 = acc[e]; b0 = e; }
        int b1 = (b0 == 0) ? 1 : 0; float l1 = acc[b1];
#pragma unroll
        for (int e = 0; e < NEXP; ++e) {
            if (e == b0 || e == b1) continue;
            if (acc[e] > l1) { l1 = acc[e]; b1 = e; }
        }
        float w0 = 1.f / (1.f + expf(l1 - l0));   // renormalized top-2 softmax
        float w1v = 1.f - w0;
        topk_idx[2 * t] = b0; topk_idx[2 * t + 1] = b1;
        topk_w[2 * t] = w0;  topk_w[2 * t + 1] = w1v;
        atomicAdd(&counts[b0], 1);
        atomicAdd(&counts[b1], 1);
    }
}

// ---------------- K2: exclusive scan + pad rows ----------------
__global__ void scan_kernel(const int* __restrict__ counts, int* __restrict__ offsets,
                            int* __restrict__ rows) {
    if (threadIdx.x == 0) {
        int off = 0;
#pragma unroll
        for (int e = 0; e < NEXP; ++e) { offsets[e] = off; off += counts[e]; }
    }
    if (threadIdx.x < SLOT_PAD) rows[NSLOT + threadIdx.x] = 0;
}

// ---------------- K3: slot assignment ----------------
__global__ void assign_kernel(const int* __restrict__ topk_idx, const int* __restrict__ offsets,
                              int* __restrict__ counts2, int* __restrict__ rows,
                              int* __restrict__ slot_of) {
    int i = blockIdx.x * 256 + threadIdx.x;   // 0..4095
    int e = topk_idx[i];
    int pos = atomicAdd(&counts2[e], 1);
    int slot = offsets[e] + pos;
    rows[slot] = i >> 1;       // token id
    slot_of[i] = slot;
}

// ---------------- K5: FAT kernel: GEMM1 (g,u)+SwiGLU -> h  ||  w2 cvt ----------------
// R14 structure (byte-identical): 2-barrier BK=64, 128x128 tile, 4 waves, 48 KB LDS,
// 8-granule XOR swizzle (verified conflict-free), T1 panel-XCD remap, fat w2-cvt.
#define G1_BLOCKS (NEXP * (NTOK / 128) * (ID / 128))   // 3584
#define CVT2_BLOCKS 1024
__global__ __launch_bounds__(256, 2)
void gemm1_kernel(const u16* __restrict__ xbf, const u16* __restrict__ w1bf,
                  const u16* __restrict__ w3bf, const int* __restrict__ counts,
                  const int* __restrict__ offsets, const int* __restrict__ rows,
                  u16* __restrict__ hbuf,
                  const float* __restrict__ w2, u16* __restrict__ w2bf) {
    __shared__ u16 As[128][64];    // 16 KB
    __shared__ u16 B1s[128][64];   // 16 KB
    __shared__ u16 B3s[128][64];   // 16 KB

    if (blockIdx.x >= G1_BLOCKS) {
        const int stride = CVT2_BLOCKS * 256;
        for (int i = (blockIdx.x - G1_BLOCKS) * 256 + threadIdx.x; i < WN / 8; i += stride) {
            f32x4 v0 = ((const f32x4*)w2)[2 * i];
            f32x4 v1 = ((const f32x4*)w2)[2 * i + 1];
            ((s16x8*)w2bf)[i] = cvt8(v0, v1);
        }
        return;
    }

    int bid = blockIdx.x;
    int gq = bid >> 7;            // 0..27
    int rm = bid & 127;
    int mt = rm >> 3;             // 0..15
    int g  = gq * 8 + (rm & 7);   // 0..223
    int e  = g / 28;              // NT = ID/128 = 28
    int nt = g - e * 28;

    int n_e = counts[e];
    int m0 = mt * 128;
    if (m0 >= n_e) return;
    int off = offsets[e];
    int n0 = nt * 128;

    int tid = threadIdx.x;
    int lane = tid & 63;
    int wid = tid >> 6;           // 0..3

    int rsub = lane >> 3;                       // 0..7
    int chunk = ((lane & 7) ^ rsub) * 8;        // pre-swizzled source offset (elems)
    int srow = wid * 32 + rsub;

    const u16 *srcA[4], *srcB1[4], *srcB3[4];
#pragma unroll
    for (int j = 0; j < 4; ++j) {
        int rl = srow + 8 * j;
        int tok = rows[off + m0 + rl];
        srcA[j]  = xbf  + (size_t)tok * HD + chunk;
        srcB1[j] = w1bf + ((size_t)e * ID + n0 + rl) * HD + chunk;
        srcB3[j] = w3bf + ((size_t)e * ID + n0 + rl) * HD + chunk;
    }

    f32x4 accg[4][4] = {}, accu[4][4] = {};
    int wm = (wid >> 1) * 64, wn = (wid & 1) * 64;
    int lr = lane & 15;
    int kk = lane >> 4;
    int ks0 = ((kk)     ^ (lr & 7)) * 8;
    int ks1 = ((4 + kk) ^ (lr & 7)) * 8;

    for (int k0 = 0; k0 < HD; k0 += 64) {        // 16 steps
#pragma unroll
        for (int j = 0; j < 4; ++j) {
            glds16(srcA[j]  + k0, &As[wid * 32 + 8 * j][0]);
            glds16(srcB1[j] + k0, &B1s[wid * 32 + 8 * j][0]);
            glds16(srcB3[j] + k0, &B3s[wid * 32 + 8 * j][0]);
        }
        __syncthreads();
        s16x8 a[4], b1[4], b3[4];
#pragma unroll
        for (int f = 0; f < 4; ++f) {
            a[f]  = *(const s16x8*)&As[wm + f * 16 + lr][ks0];
            b1[f] = *(const s16x8*)&B1s[wn + f * 16 + lr][ks0];
            b3[f] = *(const s16x8*)&B3s[wn + f * 16 + lr][ks0];
        }
#pragma unroll
        for (int fm = 0; fm < 4; ++fm)
#pragma unroll
            for (int fn = 0; fn < 4; ++fn) {
                accg[fm][fn] = __builtin_amdgcn_mfma_f32_16x16x32_bf16(a[fm], b1[fn], accg[fm][fn], 0, 0, 0);
                accu[fm][fn] = __builtin_amdgcn_mfma_f32_16x16x32_bf16(a[fm], b3[fn], accu[fm][fn], 0, 0, 0);
            }
#pragma unroll
        for (int f = 0; f < 4; ++f) {
            a[f]  = *(const s16x8*)&As[wm + f * 16 + lr][ks1];
            b1[f] = *(const s16x8*)&B1s[wn + f * 16 + lr][ks1];
            b3[f] = *(const s16x8*)&B3s[wn + f * 16 + lr][ks1];
        }
#pragma unroll
        for (int fm = 0; fm < 4; ++fm)
#pragma unroll
            for (int fn = 0; fn < 4; ++fn) {
                accg[fm][fn] = __builtin_amdgcn_mfma_f32_16x16x32_bf16(a[fm], b1[fn], accg[fm][fn], 0, 0, 0);
                accu[fm][fn] = __builtin_amdgcn_mfma_f32_16x16x32_bf16(a[fm], b3[fn], accu[fm][fn], 0, 0, 0);
            }
        __syncthreads();
    }

    int lc = lane & 15;
    int lr4 = (lane >> 4) * 4;
#pragma unroll
    for (int fm = 0; fm < 4; ++fm) {
#pragma unroll
        for (int r = 0; r < 4; ++r) {
            int row = wm + fm * 16 + lr4 + r;
            if (m0 + row < n_e) {
                size_t base = (size_t)(off + m0 + row) * ID + n0 + wn;
#pragma unroll
                for (int fn = 0; fn < 4; ++fn) {
                    float g2 = accg[fm][fn][r];
                    float u = accu[fm][fn][r];
                    float hv = g2 * u / (1.f + expf(-g2));   // silu(g)*u
                    hbuf[base + fn * 16 + lc] = f2bf(hv);
                }
            }
        }
    }
}

// ---------------- K6: GEMM2 h @ w2bf^T -> per-slot fp32, KSPLIT=1, BK=64 ----------------
// Expert-XCD remap: bid%8 = e. 1024 blocks, 56 K-steps, no partial traffic.
__global__ __launch_bounds__(256, 2)
void gemm2_kernel(const u16* __restrict__ hbuf, const u16* __restrict__ w2bf,
                  const int* __restrict__ counts, const int* __restrict__ offsets,
                  float* __restrict__ out2) {
    int bid = blockIdx.x;
    int e = bid & 7;
    int inner = bid >> 3;        // 0..127
    int mt = inner >> 3;         // 0..15
    int nt = inner & 7;          // 0..7

    int n_e = counts[e];
    int m0 = mt * 128;
    if (m0 >= n_e) return;
    int off = offsets[e];
    int n0 = nt * 128;

    __shared__ u16 As[128][64];   // 16 KB
    __shared__ u16 Bs[128][64];   // 16 KB

    int tid = threadIdx.x;
    int lane = tid & 63;
    int wid = tid >> 6;

    int rsub = lane >> 3;
    int chunk = ((lane & 7) ^ rsub) * 8;
    int srow = wid * 32 + rsub;

    const u16 *srcA[4], *srcB[4];
#pragma unroll
    for (int j = 0; j < 4; ++j) {
        int rl = srow + 8 * j;
        srcA[j] = hbuf + (size_t)(off + m0 + rl) * ID + chunk;
        srcB[j] = w2bf + ((size_t)e * HD + n0 + rl) * ID + chunk;
    }

    f32x4 acc[4][4] = {};
    int wm = (wid >> 1) * 64, wn = (wid & 1) * 64;
    int lr = lane & 15;
    int kk = lane >> 4;
    int ks0 = ((kk)     ^ (lr & 7)) * 8;
    int ks1 = ((4 + kk) ^ (lr & 7)) * 8;

    for (int k0 = 0; k0 < ID; k0 += 64) {        // 56 steps
#pragma unroll
        for (int j = 0; j < 4; ++j) {
            glds16(srcA[j] + k0, &As[wid * 32 + 8 * j][0]);
            glds16(srcB[j] + k0, &Bs[wid * 32 + 8 * j][0]);
        }
        __syncthreads();
        s16x8 a[4], b[4];
#pragma unroll
        for (int f = 0; f < 4; ++f) {
            a[f] = *(const s16x8*)&As[wm + f * 16 + lr][ks0];
            b[f] = *(const s16x8*)&Bs[wn + f * 16 + lr][ks0];
        }
#pragma unroll
        for (int fm = 0; fm < 4; ++fm)
#pragma unroll
            for (int fn = 0; fn < 4; ++fn)
                acc[fm][fn] = __builtin_amdgcn_mfma_f32_16x16x32_bf16(a[fm], b[fn], acc[fm][fn], 0, 0, 0);
#pragma unroll
        for (int f = 0; f < 4; ++f) {
            a[f] = *(const s16x8*)&As[wm + f * 16 + lr][ks1];
            b[f] = *(const s16x8*)&Bs[wn + f * 16 + lr][ks1];
        }
#pragma unroll
        for (int fm = 0; fm < 4; ++fm)
#pragma unroll
            for (int fn = 0; fn < 4; ++fn)
                acc[fm][fn] = __builtin_amdgcn_mfma_f32_16x16x32_bf16(a[fm], b[fn], acc[fm][fn], 0, 0, 0);
        __syncthreads();
    }

    int lc = lane & 15;
    int lr4 = (lane >> 4) * 4;
#pragma unroll
    for (int fm = 0; fm < 4; ++fm) {
#pragma unroll
        for (int r = 0; r < 4; ++r) {
            int row = wm + fm * 16 + lr4 + r;
            if (m0 + row < n_e) {
                float* dst = out2 + (size_t)(off + m0 + row) * HD + n0 + wn;
#pragma unroll
                for (int fn = 0; fn < 4; ++fn)
                    dst[fn * 16 + lc] = acc[fm][fn][r];
            }
        }
    }
}

// ---------------- K7: weighted combine (single partial) ----------------
__global__ void combine_kernel(const float* __restrict__ out2, const int* __restrict__ slot_of,
                               const float* __restrict__ topk_w, float* __restrict__ y) {
    int i = blockIdx.x * 256 + threadIdx.x;   // over NTOK*HD/4
    int t = i >> 8;           // HD/4 = 256 float4 per token
    int c = i & 255;
    int s0 = slot_of[2 * t], s1 = slot_of[2 * t + 1];
    float w0 = topk_w[2 * t], w1 = topk_w[2 * t + 1];
    f32x4 a = ((const f32x4*)(out2 + (size_t)s0 * HD))[c];
    f32x4 b = ((const f32x4*)(out2 + (size_t)s1 * HD))[c];
    f32x4 o;
#pragma unroll
    for (int j = 0; j < 4; ++j) o[j] = w0 * a[j] + w1 * b[j];
    ((f32x4*)(y + (size_t)t * HD))[c] = o;
}

extern "C" void kernel_launch(void* const* d_in, const int* in_sizes, int n_in,
                              void* d_out, int out_size, void* d_ws, size_t ws_size,
                              hipStream_t stream) {
    (void)in_sizes; (void)n_in; (void)out_size; (void)ws_size;
    const float* x  = (const float*)d_in[0];
    const float* wg = (const float*)d_in[1];
    const float* w1 = (const float*)d_in[2];
    const float* w3 = (const float*)d_in[3];
    const float* w2 = (const float*)d_in[4];
    float* y = (float*)d_out;

    char* ws = (char*)d_ws;
    int*   counts   = (int*)(ws + 0);       // 8 ints
    int*   counts2  = (int*)(ws + 32);      // 8 ints
    int*   offsets  = (int*)(ws + 64);      // 8 ints
    int*   topk_idx = (int*)(ws + 128);                        // 4096 ints
    float* topk_w   = (float*)(ws + 128 + (size_t)NSLOT * 4);  // 4096 floats
    int*   rows     = (int*)(ws + 128 + (size_t)NSLOT * 8);    // 4352 ints
    int*   slot_of  = (int*)(ws + 128 + (size_t)NSLOT * 8 + (size_t)NSLOT_ALLOC * 4);
    size_t off_xbf = 128 + (size_t)NSLOT * 12 + (size_t)NSLOT_ALLOC * 4;
    off_xbf = (off_xbf + 255) & ~(size_t)255;
    u16* xbf = (u16*)(ws + off_xbf);
    size_t off_h = off_xbf + (size_t)NTOK * HD * 2;
    u16* hbuf = (u16*)(ws + off_h);
    size_t off_w1 = off_h + (size_t)NSLOT_ALLOC * ID * 2;
    u16* w1bf = (u16*)(ws + off_w1);
    size_t off_w3 = off_w1 + (size_t)WN * 2;
    u16* w3bf = (u16*)(ws + off_w3);
    size_t off_w2 = off_w3 + (size_t)WN * 2;
    u16* w2bf = (u16*)(ws + off_w2);
    size_t off_o2 = off_w2 + (size_t)WN * 2;
    float* out2 = (float*)(ws + off_o2);    // single partial buffer

    init_kernel<<<1, 64, 0, stream>>>(counts);
    pre_kernel<<<RT_BLOCKS + CVT3_BLOCKS, 256, 0, stream>>>(x, wg, topk_idx, topk_w, counts,
                                                            xbf, w1, w1bf, w3, w3bf);
    scan_kernel<<<1, 256, 0, stream>>>(counts, offsets, rows);
    assign_kernel<<<NSLOT / 256, 256, 0, stream>>>(topk_idx, offsets, counts2, rows, slot_of);
    gemm1_kernel<<<G1_BLOCKS + CVT2_BLOCKS, 256, 0, stream>>>(xbf, w1bf, w3bf, counts, offsets, rows, hbuf, w2, w2bf);
    gemm2_kernel<<<NEXP * (NTOK / 128) * (HD / 128), 256, 0, stream>>>(hbuf, w2bf, counts, offsets, out2);
    combine_kernel<<<(NTOK * HD / 4) / 256, 256, 0, stream>>>(out2, slot_of, topk_w, y);
}